// Round 12
// baseline (235.103 us; speedup 1.0000x reference)
//
#include <hip/hip_runtime.h>
#include <hip/hip_bf16.h>

// B=4, Q=K=512, D=512, H=256
#define HH 256
#define DD 512
#define MM 2048                       // B*Q == B*K flattened rows
#define CSCALE 2.8853900817779268f    // 2*log2(e), folded into W (linear)

typedef __bf16 bf16x8 __attribute__((ext_vector_type(8)));
typedef float floatx4 __attribute__((ext_vector_type(4)));

// ---------------------------------------------------------------------------
// prep: (a) blocks 0..255: transpose+scale Wq,Wk -> Wt[2][256][512] bf16
//       (b) block 256: wv2 = -2*wv, sumW = sum(wv)
//       (c) blocks 257..1280: convert queries||keys f32 -> Xbf bf16 [2M]
// ---------------------------------------------------------------------------
__global__ __launch_bounds__(256) void prep_kernel(
    const float* __restrict__ Wq, const float* __restrict__ Wk,
    const float* __restrict__ wv,
    const float* __restrict__ queries, const float* __restrict__ keys,
    __bf16* __restrict__ Wt, __bf16* __restrict__ Xbf,
    float* __restrict__ wv2, float* __restrict__ sumWp)
{
  const int bx = blockIdx.x;
  if (bx < 256) {
    const int mat  = bx >> 7;
    const int tile = bx & 127;
    const int kt = tile & 15;    // 512/32 k-tiles
    const int nt = tile >> 4;    // 256/32 n-tiles
    const float* __restrict__ W = mat ? Wk : Wq;
    __bf16* __restrict__ Wo = Wt + (size_t)mat * HH * DD;
    __shared__ float lds[32][33];
    const int i = threadIdx.x >> 5;   // 0..7
    const int j = threadIdx.x & 31;   // 0..31
    const int k0 = kt * 32, n0 = nt * 32;
#pragma unroll
    for (int p = 0; p < 4; ++p)
      lds[i + p * 8][j] = W[(k0 + i + p * 8) * HH + n0 + j];
    __syncthreads();
#pragma unroll
    for (int p = 0; p < 4; ++p) {
      const int n = i + p * 8;
      Wo[(n0 + n) * DD + k0 + j] = (__bf16)(lds[j][n] * CSCALE);
    }
  } else if (bx == 256) {
    __shared__ float red[256];
    const int t = threadIdx.x;
    float w = wv[t];
    wv2[t] = -2.0f * w;
    red[t] = w;
    __syncthreads();
    for (int s = 128; s > 0; s >>= 1) {
      if (t < s) red[t] += red[t + s];
      __syncthreads();
    }
    if (t == 0) *sumWp = red[0];
  } else {
    const int blk = bx - 257;                       // 0..1023
    const size_t dst = (size_t)blk * 2048 + threadIdx.x * 8;
    const float* __restrict__ src =
        (blk < 512) ? (queries + dst) : (keys + dst - (size_t)1048576);
    float4 a = *(const float4*)(src);
    float4 b = *(const float4*)(src + 4);
    bf16x8 v;
    v[0] = (__bf16)a.x; v[1] = (__bf16)a.y; v[2] = (__bf16)a.z; v[3] = (__bf16)a.w;
    v[4] = (__bf16)b.x; v[5] = (__bf16)b.y; v[6] = (__bf16)b.z; v[7] = (__bf16)b.w;
    *(bf16x8*)(Xbf + dst) = v;
  }
}

// ---------------------------------------------------------------------------
// proj: P = Xbf(2048x512 bf16) @ Wt^T (bf16, prescaled by 2*log2e).
// Block = 4 waves: wave (tw, ks) computes 16x32 tile tw over K-half ks.
// LDS combine, then exp2 epilogue:
//   z==0: queries -> eq = exp2(qc) f32  [2048][256]
//   z==1: keys    -> ek = exp2(kc) BF16 [m/16][hq(64)][m%16][4]
//         (score reads all 32 hq of a half via IMMEDIATE offsets)
// Fragment layouts (HW-verified rounds 1-11):
//   A: lane A[m=lane&15][k=(lane>>4)*8+j]; B: B[k=(lane>>4)*8+j][n=lane&15]
//   D: reg i -> row=(lane>>4)*4+i, col=lane&15
// ---------------------------------------------------------------------------
__global__ __launch_bounds__(256, 4) void proj_kernel(
    const __bf16* __restrict__ Xbf, const __bf16* __restrict__ Wt,
    float* __restrict__ eqp, __bf16* __restrict__ ekb)
{
  const int w    = threadIdx.x >> 6;
  const int lane = threadIdx.x & 63;
  const int quad = lane >> 4;
  const int r    = lane & 15;
  const int tw = w & 1;        // which 16-row tile
  const int ks = w >> 1;       // which K half
  const bool is_k = (blockIdx.z != 0);
  const __bf16* __restrict__ X  = Xbf + (is_k ? (size_t)1048576 : 0);
  const __bf16* __restrict__ Wb = Wt + (is_k ? (size_t)HH * DD : 0);

  const int m0 = blockIdx.x * 32 + tw * 16;
  const int n0 = blockIdx.y * 32;

  floatx4 acc0 = {0.f, 0.f, 0.f, 0.f};
  floatx4 acc1 = {0.f, 0.f, 0.f, 0.f};
  const __bf16* arow = X + (size_t)(m0 + r) * DD + ks * 256 + quad * 8;
  const __bf16* b0   = Wb + (size_t)(n0 + r) * DD + ks * 256 + quad * 8;
  const __bf16* b1   = b0 + 16 * DD;

#pragma unroll
  for (int kk = 0; kk < 256; kk += 32) {
    bf16x8 af  = *(const bf16x8*)(arow + kk);
    bf16x8 bf0 = *(const bf16x8*)(b0 + kk);
    bf16x8 bf1 = *(const bf16x8*)(b1 + kk);
    acc0 = __builtin_amdgcn_mfma_f32_16x16x32_bf16(af, bf0, acc0, 0, 0, 0);
    acc1 = __builtin_amdgcn_mfma_f32_16x16x32_bf16(af, bf1, acc1, 0, 0, 0);
  }

  __shared__ float part[2][64][9];   // +1 pad: conflict-free combine
  if (ks == 1) {
#pragma unroll
    for (int i = 0; i < 4; ++i) {
      part[tw][lane][i]     = acc0[i];
      part[tw][lane][4 + i] = acc1[i];
    }
  }
  __syncthreads();
  if (ks == 0) {
#pragma unroll
    for (int i = 0; i < 4; ++i) {
      acc0[i] += part[tw][lane][i];
      acc1[i] += part[tw][lane][4 + i];
    }
    const int mrow = m0 + quad * 4;
    if (!is_k) {
#pragma unroll
      for (int i = 0; i < 4; ++i) {
        eqp[(size_t)(mrow + i) * HH + n0 + r] =
            __builtin_amdgcn_exp2f(acc0[i]);
        eqp[(size_t)(mrow + i) * HH + n0 + 16 + r] =
            __builtin_amdgcn_exp2f(acc1[i]);
      }
    } else {
      const int na = n0 + r, nb = n0 + 16 + r;
#pragma unroll
      for (int i = 0; i < 4; ++i) {
        const int m = mrow + i;
        ekb[(((size_t)(m >> 4) * 64 + (na >> 2)) * 16 + (m & 15)) * 4 + (na & 3)] =
            (__bf16)__builtin_amdgcn_exp2f(acc0[i]);
        ekb[(((size_t)(m >> 4) * 64 + (nb >> 2)) * 16 + (m & 15)) * 4 + (nb & 3)] =
            (__bf16)__builtin_amdgcn_exp2f(acc1[i]);
      }
    }
  }
}

// ---------------------------------------------------------------------------
// score (R12): TK=2 — the broadcast-work invariant breaker.
// Pipe model (fits R3/R8/R10 within ~20%): LDS is ONE per-CU pipe,
// ds_read_b128 ~12 cyc; eq/wv broadcast work = waves x reads is invariant
// in TQ — which is why R3..R11 score never moved. TK=2 (two k-columns per
// thread) halves wave count at fixed per-wave broadcast reads:
// LDS/CU = 32 waves x 32 hq x 3 b128 x 12 = 15.4 us (was 25.6).
//   out[b,q,k] = sumW + sum_{quads} [n01*p23 + n23*p01] * rcp(p01*p23)
//   u_i = 1 + eq*ek; n01 = w'0*u1 + w'1*u0; w' = -2*wv  (exact tanh algebra)
// 512-thr blocks, h-split (waves 0-3 / 4-7), LDS combine (no atomics - R9).
// Block covers ALL of K (256 thr x TK=2); grid (1,256,4) = 1024 blocks
// = 4 blocks/CU -> 8 waves/SIMD. ek loads: imm-offset dwordx2 x2 per hq.
// ---------------------------------------------------------------------------
__device__ __forceinline__ float quad_term(
    float ek0, float ek1, float ek2, float ek3,
    float4 e, float4 w, float acc)
{
  float u0 = fmaf(e.x, ek0, 1.0f);
  float u1 = fmaf(e.y, ek1, 1.0f);
  float u2 = fmaf(e.z, ek2, 1.0f);
  float u3 = fmaf(e.w, ek3, 1.0f);
  float p01 = u0 * u1;
  float p23 = u2 * u3;
  float n01 = fmaf(w.y, u0, w.x * u1);
  float n23 = fmaf(w.w, u2, w.z * u3);
  float N   = fmaf(n23, p01, n01 * p23);
  float r   = __builtin_amdgcn_rcpf(p01 * p23);
  return fmaf(N, r, acc);
}

__global__ __launch_bounds__(512, 8) void score_kernel(
    const float* __restrict__ eqp, const uint2* __restrict__ ekb,
    const float* __restrict__ wv2, const float* __restrict__ sumWp,
    float* __restrict__ out)
{
  __shared__ __align__(16) float eqs[2][2][128];  // [hb][q-row][h] 2 KB
  __shared__ __align__(16) float wvs[2][128];     // 1 KB
  __shared__ __align__(16) float part[4][256];    // hb=1 partials 4 KB

  const int tid = threadIdx.x;
  const int t   = tid & 255;          // k lane (k0 = t, k1 = t + 256)
  const int hb  = tid >> 8;           // h half (wave-uniform: waves 0-3 / 4-7)
  const int b   = blockIdx.z;
  const int q0  = blockIdx.y * 2;

  // Stage 2 eq rows (2 KB) + wv2 (1 KB), coalesced.
  {
    const int c = tid & 255;          // h column
    const int r = tid >> 8;           // row 0,1
    eqs[c >> 7][r][c & 127] = eqp[(size_t)(b * 512 + q0 + r) * HH + c];
    if (tid < 256) wvs[tid >> 7][tid & 127] = wv2[tid];
  }
  __syncthreads();

  const int m0 = b * 512 + t;         // key row of k0 in [0,2048)
  const int m1 = m0 + 256;            // key row of k1
  const uint2* __restrict__ kptr0 =
      ekb + ((size_t)(m0 >> 4) * 64 + hb * 32) * 16 + (m0 & 15);
  const uint2* __restrict__ kptr1 =
      ekb + ((size_t)(m1 >> 4) * 64 + hb * 32) * 16 + (m1 & 15);

  float a00 = 0.f, a01 = 0.f, a10 = 0.f, a11 = 0.f;   // a[q][k]

  for (int c = 0; c < 8; ++c) {       // 8 chunks x 4 hq = 32 hq per half
    uint2 kb0[4], kb1[4];
#pragma unroll
    for (int i = 0; i < 4; ++i) {     // 8 imm-offset loads batched in flight
      kb0[i] = kptr0[(c * 4 + i) * 16];
      kb1[i] = kptr1[(c * 4 + i) * 16];
    }
#pragma unroll
    for (int i = 0; i < 4; ++i) {
      const int hq = c * 4 + i;
      float4 w4 = *(const float4*)&wvs[hb][hq * 4];       // ds broadcast
      float4 e0 = *(const float4*)&eqs[hb][0][hq * 4];    // ds broadcast
      float4 e1 = *(const float4*)&eqs[hb][1][hq * 4];    // ds broadcast
      float p0 = __uint_as_float(kb0[i].x << 16);
      float p1 = __uint_as_float(kb0[i].x & 0xffff0000u);
      float p2 = __uint_as_float(kb0[i].y << 16);
      float p3 = __uint_as_float(kb0[i].y & 0xffff0000u);
      a00 = quad_term(p0, p1, p2, p3, e0, w4, a00);
      a10 = quad_term(p0, p1, p2, p3, e1, w4, a10);
      float s0 = __uint_as_float(kb1[i].x << 16);
      float s1 = __uint_as_float(kb1[i].x & 0xffff0000u);
      float s2 = __uint_as_float(kb1[i].y << 16);
      float s3 = __uint_as_float(kb1[i].y & 0xffff0000u);
      a01 = quad_term(s0, s1, s2, s3, e0, w4, a01);
      a11 = quad_term(s0, s1, s2, s3, e1, w4, a11);
    }
  }

  if (hb == 1) {
    part[0][t] = a00; part[1][t] = a01;
    part[2][t] = a10; part[3][t] = a11;
  }
  __syncthreads();
  if (hb == 0) {
    const float sumW = *sumWp;
    float* ob = out + ((size_t)(b * 512 + q0)) * 512;
    ob[t]             = sumW + a00 + part[0][t];
    ob[t + 256]       = sumW + a01 + part[1][t];
    ob[512 + t]       = sumW + a10 + part[2][t];
    ob[512 + t + 256] = sumW + a11 + part[3][t];
  }
}

// ---------------------------------------------------------------------------
extern "C" void kernel_launch(void* const* d_in, const int* in_sizes, int n_in,
                              void* d_out, int out_size, void* d_ws, size_t ws_size,
                              hipStream_t stream) {
  (void)in_sizes; (void)n_in; (void)out_size; (void)ws_size;
  const float* queries = (const float*)d_in[0];
  const float* Keys    = (const float*)d_in[1];
  const float* Wq      = (const float*)d_in[2];
  const float* Wk      = (const float*)d_in[3];
  const float* wv      = (const float*)d_in[4];
  float* out = (float*)d_out;

  // ws layout (~8 MB of the 256 MB workspace):
  //   [0, 512K)      Wt   bf16 [2][256][512]
  //   [512K, +1K)    wv2  f32 [256]  (= -2*wv)
  //   [513K, +4)     sumW
  //   [1M, 5M)       Xbf  bf16 [2][2048][512]  (queries||keys, converted)
  //   [5M, 7M)       eq   f32  [2048][256]
  //   [7M, 8M)       ekb  bf16 [m/16][64][16][4]
  char* ws = (char*)d_ws;
  __bf16* Wt    = (__bf16*)ws;
  float*  wv2   = (float*)(ws + (512 << 10));
  float*  sumWp = (float*)(ws + (513 << 10));
  __bf16* Xbf   = (__bf16*)(ws + (1 << 20));
  float*  eqp   = (float*)(ws + (5ull << 20));
  __bf16* ekb   = (__bf16*)(ws + (7ull << 20));

  prep_kernel<<<dim3(1281), 256, 0, stream>>>(
      Wq, Wk, wv, queries, Keys, Wt, Xbf, wv2, sumWp);
  proj_kernel<<<dim3(64, 8, 2), 256, 0, stream>>>(Xbf, Wt, eqp, ekb);
  score_kernel<<<dim3(1, 256, 4), 512, 0, stream>>>(
      eqp, (const uint2*)ekb, wv2, sumWp, out);
}

// Round 13
// 109.498 us; speedup vs baseline: 2.1471x; 2.1471x over previous
//
#include <hip/hip_runtime.h>
#include <hip/hip_bf16.h>

// B=4, Q=K=512, D=512, H=256
#define HH 256
#define DD 512
#define MM 2048                       // B*Q == B*K flattened rows
#define CSCALE 2.8853900817779268f    // 2*log2(e), folded into W (linear)

typedef __bf16 bf16x8 __attribute__((ext_vector_type(8)));
typedef float floatx4 __attribute__((ext_vector_type(4)));

// ---------------------------------------------------------------------------
// prep: (a) blocks 0..255: transpose+scale Wq,Wk -> Wt[2][256][512] bf16
//       (b) block 256: wv2 = -2*wv, sumW = sum(wv)
//       (c) blocks 257..1280: convert queries||keys f32 -> Xbf bf16 [2M]
// ---------------------------------------------------------------------------
__global__ __launch_bounds__(256) void prep_kernel(
    const float* __restrict__ Wq, const float* __restrict__ Wk,
    const float* __restrict__ wv,
    const float* __restrict__ queries, const float* __restrict__ keys,
    __bf16* __restrict__ Wt, __bf16* __restrict__ Xbf,
    float* __restrict__ wv2, float* __restrict__ sumWp)
{
  const int bx = blockIdx.x;
  if (bx < 256) {
    const int mat  = bx >> 7;
    const int tile = bx & 127;
    const int kt = tile & 15;    // 512/32 k-tiles
    const int nt = tile >> 4;    // 256/32 n-tiles
    const float* __restrict__ W = mat ? Wk : Wq;
    __bf16* __restrict__ Wo = Wt + (size_t)mat * HH * DD;
    __shared__ float lds[32][33];
    const int i = threadIdx.x >> 5;   // 0..7
    const int j = threadIdx.x & 31;   // 0..31
    const int k0 = kt * 32, n0 = nt * 32;
#pragma unroll
    for (int p = 0; p < 4; ++p)
      lds[i + p * 8][j] = W[(k0 + i + p * 8) * HH + n0 + j];
    __syncthreads();
#pragma unroll
    for (int p = 0; p < 4; ++p) {
      const int n = i + p * 8;
      Wo[(n0 + n) * DD + k0 + j] = (__bf16)(lds[j][n] * CSCALE);
    }
  } else if (bx == 256) {
    __shared__ float red[256];
    const int t = threadIdx.x;
    float w = wv[t];
    wv2[t] = -2.0f * w;
    red[t] = w;
    __syncthreads();
    for (int s = 128; s > 0; s >>= 1) {
      if (t < s) red[t] += red[t + s];
      __syncthreads();
    }
    if (t == 0) *sumWp = red[0];
  } else {
    const int blk = bx - 257;                       // 0..1023
    const size_t dst = (size_t)blk * 2048 + threadIdx.x * 8;
    const float* __restrict__ src =
        (blk < 512) ? (queries + dst) : (keys + dst - (size_t)1048576);
    float4 a = *(const float4*)(src);
    float4 b = *(const float4*)(src + 4);
    bf16x8 v;
    v[0] = (__bf16)a.x; v[1] = (__bf16)a.y; v[2] = (__bf16)a.z; v[3] = (__bf16)a.w;
    v[4] = (__bf16)b.x; v[5] = (__bf16)b.y; v[6] = (__bf16)b.z; v[7] = (__bf16)b.w;
    *(bf16x8*)(Xbf + dst) = v;
  }
}

// ---------------------------------------------------------------------------
// proj: P = Xbf(2048x512 bf16) @ Wt^T (bf16, prescaled by 2*log2e).
// Block = 4 waves: wave (tw, ks) computes 16x32 tile tw over K-half ks.
// LDS combine, then exp2 epilogue:
//   z==0: queries -> eq = exp2(qc) f32  [2048][256]
//   z==1: keys    -> ek = exp2(kc) BF16 [m/16][hq(64)][m%16][4]
//         (score reads all 32 hq of a half via IMMEDIATE offsets)
// Fragment layouts (HW-verified rounds 1-12):
//   A: lane A[m=lane&15][k=(lane>>4)*8+j]; B: B[k=(lane>>4)*8+j][n=lane&15]
//   D: reg i -> row=(lane>>4)*4+i, col=lane&15
// ---------------------------------------------------------------------------
__global__ __launch_bounds__(256, 4) void proj_kernel(
    const __bf16* __restrict__ Xbf, const __bf16* __restrict__ Wt,
    float* __restrict__ eqp, __bf16* __restrict__ ekb)
{
  const int w    = threadIdx.x >> 6;
  const int lane = threadIdx.x & 63;
  const int quad = lane >> 4;
  const int r    = lane & 15;
  const int tw = w & 1;        // which 16-row tile
  const int ks = w >> 1;       // which K half
  const bool is_k = (blockIdx.z != 0);
  const __bf16* __restrict__ X  = Xbf + (is_k ? (size_t)1048576 : 0);
  const __bf16* __restrict__ Wb = Wt + (is_k ? (size_t)HH * DD : 0);

  const int m0 = blockIdx.x * 32 + tw * 16;
  const int n0 = blockIdx.y * 32;

  floatx4 acc0 = {0.f, 0.f, 0.f, 0.f};
  floatx4 acc1 = {0.f, 0.f, 0.f, 0.f};
  const __bf16* arow = X + (size_t)(m0 + r) * DD + ks * 256 + quad * 8;
  const __bf16* b0   = Wb + (size_t)(n0 + r) * DD + ks * 256 + quad * 8;
  const __bf16* b1   = b0 + 16 * DD;

#pragma unroll
  for (int kk = 0; kk < 256; kk += 32) {
    bf16x8 af  = *(const bf16x8*)(arow + kk);
    bf16x8 bf0 = *(const bf16x8*)(b0 + kk);
    bf16x8 bf1 = *(const bf16x8*)(b1 + kk);
    acc0 = __builtin_amdgcn_mfma_f32_16x16x32_bf16(af, bf0, acc0, 0, 0, 0);
    acc1 = __builtin_amdgcn_mfma_f32_16x16x32_bf16(af, bf1, acc1, 0, 0, 0);
  }

  __shared__ float part[2][64][9];   // +1 pad: conflict-free combine
  if (ks == 1) {
#pragma unroll
    for (int i = 0; i < 4; ++i) {
      part[tw][lane][i]     = acc0[i];
      part[tw][lane][4 + i] = acc1[i];
    }
  }
  __syncthreads();
  if (ks == 0) {
#pragma unroll
    for (int i = 0; i < 4; ++i) {
      acc0[i] += part[tw][lane][i];
      acc1[i] += part[tw][lane][4 + i];
    }
    const int mrow = m0 + quad * 4;
    if (!is_k) {
#pragma unroll
      for (int i = 0; i < 4; ++i) {
        eqp[(size_t)(mrow + i) * HH + n0 + r] =
            __builtin_amdgcn_exp2f(acc0[i]);
        eqp[(size_t)(mrow + i) * HH + n0 + 16 + r] =
            __builtin_amdgcn_exp2f(acc1[i]);
      }
    } else {
      const int na = n0 + r, nb = n0 + 16 + r;
#pragma unroll
      for (int i = 0; i < 4; ++i) {
        const int m = mrow + i;
        ekb[(((size_t)(m >> 4) * 64 + (na >> 2)) * 16 + (m & 15)) * 4 + (na & 3)] =
            (__bf16)__builtin_amdgcn_exp2f(acc0[i]);
        ekb[(((size_t)(m >> 4) * 64 + (nb >> 2)) * 16 + (m & 15)) * 4 + (nb & 3)] =
            (__bf16)__builtin_amdgcn_exp2f(acc1[i]);
      }
    }
  }
}

// ---------------------------------------------------------------------------
// score (R13): TK=2 retry, spill-proofed. R12's version hit the 64-VGPR cap
// of launch_bounds(512,8) (8 hoisted loads + 2 ptrs + dup unpack) and
// spilled to scratch: WRITE_SIZE 4->466 MB, VALUBusy 12%, 168 us. Fixes:
// outer loop unroll-pinned to 1, batch 4 loads (2 per pointer), 16x2 hq.
// Live regs ~45 < 64.
// Pipe model (fits R3/R8/R10): LDS is ONE per-CU pipe, ds_read_b128 ~12cyc;
// eq/wv broadcast work is invariant in TQ; TK=2 halves it:
// 3 b128/hq x 32 hq x 32 waves/CU x 12 = 15.4 us (R10: 25.6).
//   out[b,q,k] = sumW + sum_{quads} [n01*p23 + n23*p01] * rcp(p01*p23)
//   u_i = 1 + eq*ek; n01 = w'0*u1 + w'1*u0; w' = -2*wv  (exact tanh algebra)
// 512-thr blocks, h-split (waves 0-3 / 4-7), LDS combine (no atomics - R9).
// Grid (1,256,4) = 1024 blocks = 4 blocks/CU -> 8 waves/SIMD.
// ---------------------------------------------------------------------------
__device__ __forceinline__ float quad_term(
    float ek0, float ek1, float ek2, float ek3,
    float4 e, float4 w, float acc)
{
  float u0 = fmaf(e.x, ek0, 1.0f);
  float u1 = fmaf(e.y, ek1, 1.0f);
  float u2 = fmaf(e.z, ek2, 1.0f);
  float u3 = fmaf(e.w, ek3, 1.0f);
  float p01 = u0 * u1;
  float p23 = u2 * u3;
  float n01 = fmaf(w.y, u0, w.x * u1);
  float n23 = fmaf(w.w, u2, w.z * u3);
  float N   = fmaf(n23, p01, n01 * p23);
  float r   = __builtin_amdgcn_rcpf(p01 * p23);
  return fmaf(N, r, acc);
}

__global__ __launch_bounds__(512, 8) void score_kernel(
    const float* __restrict__ eqp, const uint2* __restrict__ ekb,
    const float* __restrict__ wv2, const float* __restrict__ sumWp,
    float* __restrict__ out)
{
  __shared__ __align__(16) float eqs[2][2][128];  // [hb][q-row][h] 2 KB
  __shared__ __align__(16) float wvs[2][128];     // 1 KB
  __shared__ __align__(16) float part[4][256];    // hb=1 partials 4 KB

  const int tid = threadIdx.x;
  const int t   = tid & 255;          // k lane (k0 = t, k1 = t + 256)
  const int hb  = tid >> 8;           // h half (wave-uniform: waves 0-3 / 4-7)
  const int b   = blockIdx.z;
  const int q0  = blockIdx.y * 2;

  // Stage 2 eq rows (2 KB) + wv2 (1 KB), coalesced.
  {
    const int c = tid & 255;          // h column
    const int r = tid >> 8;           // row 0,1
    eqs[c >> 7][r][c & 127] = eqp[(size_t)(b * 512 + q0 + r) * HH + c];
    if (tid < 256) wvs[tid >> 7][tid & 127] = wv2[tid];
  }
  __syncthreads();

  const int m0 = b * 512 + t;         // key row of k0 in [0,2048)
  const int m1 = m0 + 256;            // key row of k1
  const uint2* __restrict__ kptr0 =
      ekb + ((size_t)(m0 >> 4) * 64 + hb * 32) * 16 + (m0 & 15);
  const uint2* __restrict__ kptr1 =
      ekb + ((size_t)(m1 >> 4) * 64 + hb * 32) * 16 + (m1 & 15);

  float a00 = 0.f, a01 = 0.f, a10 = 0.f, a11 = 0.f;   // a[q][k]

#pragma unroll 1
  for (int c = 0; c < 16; ++c) {      // 16 chunks x 2 hq = 32 hq per half
    uint2 kb0[2], kb1[2];
    kb0[0] = kptr0[(c * 2 + 0) * 16];       // 4 imm-offset loads in flight
    kb0[1] = kptr0[(c * 2 + 1) * 16];
    kb1[0] = kptr1[(c * 2 + 0) * 16];
    kb1[1] = kptr1[(c * 2 + 1) * 16];
#pragma unroll
    for (int i = 0; i < 2; ++i) {
      const int hq = c * 2 + i;
      float4 w4 = *(const float4*)&wvs[hb][hq * 4];       // ds broadcast
      float4 e0 = *(const float4*)&eqs[hb][0][hq * 4];    // ds broadcast
      float4 e1 = *(const float4*)&eqs[hb][1][hq * 4];    // ds broadcast
      float p0 = __uint_as_float(kb0[i].x << 16);
      float p1 = __uint_as_float(kb0[i].x & 0xffff0000u);
      float p2 = __uint_as_float(kb0[i].y << 16);
      float p3 = __uint_as_float(kb0[i].y & 0xffff0000u);
      a00 = quad_term(p0, p1, p2, p3, e0, w4, a00);
      a10 = quad_term(p0, p1, p2, p3, e1, w4, a10);
      float s0 = __uint_as_float(kb1[i].x << 16);
      float s1 = __uint_as_float(kb1[i].x & 0xffff0000u);
      float s2 = __uint_as_float(kb1[i].y << 16);
      float s3 = __uint_as_float(kb1[i].y & 0xffff0000u);
      a01 = quad_term(s0, s1, s2, s3, e0, w4, a01);
      a11 = quad_term(s0, s1, s2, s3, e1, w4, a11);
    }
  }

  if (hb == 1) {
    part[0][t] = a00; part[1][t] = a01;
    part[2][t] = a10; part[3][t] = a11;
  }
  __syncthreads();
  if (hb == 0) {
    const float sumW = *sumWp;
    float* ob = out + ((size_t)(b * 512 + q0)) * 512;
    ob[t]             = sumW + a00 + part[0][t];
    ob[t + 256]       = sumW + a01 + part[1][t];
    ob[512 + t]       = sumW + a10 + part[2][t];
    ob[512 + t + 256] = sumW + a11 + part[3][t];
  }
}

// ---------------------------------------------------------------------------
extern "C" void kernel_launch(void* const* d_in, const int* in_sizes, int n_in,
                              void* d_out, int out_size, void* d_ws, size_t ws_size,
                              hipStream_t stream) {
  (void)in_sizes; (void)n_in; (void)out_size; (void)ws_size;
  const float* queries = (const float*)d_in[0];
  const float* Keys    = (const float*)d_in[1];
  const float* Wq      = (const float*)d_in[2];
  const float* Wk      = (const float*)d_in[3];
  const float* wv      = (const float*)d_in[4];
  float* out = (float*)d_out;

  // ws layout (~8 MB of the 256 MB workspace):
  //   [0, 512K)      Wt   bf16 [2][256][512]
  //   [512K, +1K)    wv2  f32 [256]  (= -2*wv)
  //   [513K, +4)     sumW
  //   [1M, 5M)       Xbf  bf16 [2][2048][512]  (queries||keys, converted)
  //   [5M, 7M)       eq   f32  [2048][256]
  //   [7M, 8M)       ekb  bf16 [m/16][64][16][4]
  char* ws = (char*)d_ws;
  __bf16* Wt    = (__bf16*)ws;
  float*  wv2   = (float*)(ws + (512 << 10));
  float*  sumWp = (float*)(ws + (513 << 10));
  __bf16* Xbf   = (__bf16*)(ws + (1 << 20));
  float*  eqp   = (float*)(ws + (5ull << 20));
  __bf16* ekb   = (__bf16*)(ws + (7ull << 20));

  prep_kernel<<<dim3(1281), 256, 0, stream>>>(
      Wq, Wk, wv, queries, Keys, Wt, Xbf, wv2, sumWp);
  proj_kernel<<<dim3(64, 8, 2), 256, 0, stream>>>(Xbf, Wt, eqp, ekb);
  score_kernel<<<dim3(1, 256, 4), 512, 0, stream>>>(
      eqp, (const uint2*)ekb, wv2, sumWp, out);
}